// Round 4
// baseline (90.877 us; speedup 1.0000x reference)
//
#include <hip/hip_runtime.h>

// TripletLoss: B=384, D=1024 fp32, 16 classes, margin=1.
// H[i][j] = sq[j] - 2*dot(e_i,e_j); loss = relu(H[a,p]-H[a,n]+margin) (sq[a] cancels).
// R4: gram exploits symmetry: 6 upper-triangle 128x128 tiles x Z=32 split-K
// = 192 blocks; 8x8 register blocking (1B LDS/MAC); K-major LDS with phys-row
// swizzle pr=r+4*(r>>5) (LDK=140) -> conflict-free ds_write_b32 staging AND
// ds_read_b128 fragments; off-diagonal tiles dual-write acc and acc^T
// (bitwise identical by symmetry of the dot product). Single stage, 1 barrier.
// triplet: per-anchor 128-thread blocks, P[r][z][c] layout, ticket finalize.

constexpr int BN  = 384;
constexpr int DIM = 1024;
constexpr float MARGIN = 1.0f;
constexpr int LDST = 140;   // phys-row stride (floats) per k-slice; 140*4B, 16B-aligned

// ---------------------------------------------------------------- gram (sym, split-K)
// grid = 6*Z blocks, 256 threads. tile = b%6 -> (ti,tj) upper triangle; z = b/6.
__global__ __launch_bounds__(256) void gram_kernel(
    const float* __restrict__ E, float* __restrict__ P,
    float* __restrict__ sqpart, float* __restrict__ total,
    int* __restrict__ cnt, int* __restrict__ ticket, int KC, int NZ) {
    __shared__ float Ast[32 * LDST];
    __shared__ float Bst[32 * LDST];
    const int t    = threadIdx.x;
    const int tile = blockIdx.x % 6;
    const int z    = blockIdx.x / 6;
    const int ti   = (tile < 3) ? 0 : ((tile < 5) ? 1 : 2);
    const int tj   = (tile < 3) ? tile : ((tile < 5) ? tile - 2 : 2);
    const int i0   = ti * 128, j0 = tj * 128;

    if (blockIdx.x == 0 && t == 0) { *total = 0.f; *cnt = 0; *ticket = 0; }

    // staging: thread t covers row r=t>>1, 64B half h=t&1 (consecutive per lane)
    const int r  = t >> 1;
    const int h  = t & 1;
    const int pr = r + 4 * (r >> 5);          // phys row (swizzle)
    const float* Ab = E + (size_t)(i0 + r) * DIM + (size_t)z * KC + h * 16;
    const float* Bb = E + (size_t)(j0 + r) * DIM + (size_t)z * KC + h * 16;

    const int tx = t & 15, ty = t >> 4;
    const int pa = 8 * ty + 4 * (ty >> 2);
    const int pb = 8 * tx + 4 * (tx >> 2);

    float acc[8][8] = {};

    for (int kt = 0; kt < KC; kt += 32) {
        float4 av0 = *(const float4*)(Ab + kt);
        float4 av1 = *(const float4*)(Ab + kt + 4);
        float4 av2 = *(const float4*)(Ab + kt + 8);
        float4 av3 = *(const float4*)(Ab + kt + 12);
        float4 bv0 = *(const float4*)(Bb + kt);
        float4 bv1 = *(const float4*)(Bb + kt + 4);
        float4 bv2 = *(const float4*)(Bb + kt + 8);
        float4 bv3 = *(const float4*)(Bb + kt + 12);
        if (kt) __syncthreads();              // LDS reuse guard (only if >1 chunk)
        const int kb = 16 * h;
        Ast[(kb + 0)  * LDST + pr] = av0.x; Ast[(kb + 1)  * LDST + pr] = av0.y;
        Ast[(kb + 2)  * LDST + pr] = av0.z; Ast[(kb + 3)  * LDST + pr] = av0.w;
        Ast[(kb + 4)  * LDST + pr] = av1.x; Ast[(kb + 5)  * LDST + pr] = av1.y;
        Ast[(kb + 6)  * LDST + pr] = av1.z; Ast[(kb + 7)  * LDST + pr] = av1.w;
        Ast[(kb + 8)  * LDST + pr] = av2.x; Ast[(kb + 9)  * LDST + pr] = av2.y;
        Ast[(kb + 10) * LDST + pr] = av2.z; Ast[(kb + 11) * LDST + pr] = av2.w;
        Ast[(kb + 12) * LDST + pr] = av3.x; Ast[(kb + 13) * LDST + pr] = av3.y;
        Ast[(kb + 14) * LDST + pr] = av3.z; Ast[(kb + 15) * LDST + pr] = av3.w;
        Bst[(kb + 0)  * LDST + pr] = bv0.x; Bst[(kb + 1)  * LDST + pr] = bv0.y;
        Bst[(kb + 2)  * LDST + pr] = bv0.z; Bst[(kb + 3)  * LDST + pr] = bv0.w;
        Bst[(kb + 4)  * LDST + pr] = bv1.x; Bst[(kb + 5)  * LDST + pr] = bv1.y;
        Bst[(kb + 6)  * LDST + pr] = bv1.z; Bst[(kb + 7)  * LDST + pr] = bv1.w;
        Bst[(kb + 8)  * LDST + pr] = bv2.x; Bst[(kb + 9)  * LDST + pr] = bv2.y;
        Bst[(kb + 10) * LDST + pr] = bv2.z; Bst[(kb + 11) * LDST + pr] = bv2.w;
        Bst[(kb + 12) * LDST + pr] = bv3.x; Bst[(kb + 13) * LDST + pr] = bv3.y;
        Bst[(kb + 14) * LDST + pr] = bv3.z; Bst[(kb + 15) * LDST + pr] = bv3.w;
        __syncthreads();
#pragma unroll
        for (int kk = 0; kk < 32; ++kk) {
            const float4 a0 = *(const float4*)&Ast[kk * LDST + pa];
            const float4 a1 = *(const float4*)&Ast[kk * LDST + pa + 4];
            const float4 b0 = *(const float4*)&Bst[kk * LDST + pb];
            const float4 b1 = *(const float4*)&Bst[kk * LDST + pb + 4];
            const float aa[8] = {a0.x, a0.y, a0.z, a0.w, a1.x, a1.y, a1.z, a1.w};
            const float bb[8] = {b0.x, b0.y, b0.z, b0.w, b1.x, b1.y, b1.z, b1.w};
#pragma unroll
            for (int i2 = 0; i2 < 8; ++i2)
#pragma unroll
                for (int j2 = 0; j2 < 8; ++j2)
                    acc[i2][j2] += aa[i2] * bb[j2];
        }
    }

    const size_t ZBN = (size_t)NZ * BN;
    const int row0 = i0 + 8 * ty, col0 = j0 + 8 * tx;
#pragma unroll
    for (int i2 = 0; i2 < 8; ++i2) {
        float* dst = &P[(size_t)(row0 + i2) * ZBN + (size_t)z * BN + col0];
        *(float4*)(dst)     = make_float4(acc[i2][0], acc[i2][1], acc[i2][2], acc[i2][3]);
        *(float4*)(dst + 4) = make_float4(acc[i2][4], acc[i2][5], acc[i2][6], acc[i2][7]);
    }
    if (ti != tj) {                           // transposed dual-write (exact: dot sym)
#pragma unroll
        for (int j2 = 0; j2 < 8; ++j2) {
            float* dst = &P[(size_t)(col0 + j2) * ZBN + (size_t)z * BN + row0];
            *(float4*)(dst)     = make_float4(acc[0][j2], acc[1][j2], acc[2][j2], acc[3][j2]);
            *(float4*)(dst + 4) = make_float4(acc[4][j2], acc[5][j2], acc[6][j2], acc[7][j2]);
        }
    } else if (tx == ty) {                    // diagonal -> sq partials
#pragma unroll
        for (int i2 = 0; i2 < 8; ++i2)
            sqpart[z * BN + row0 + i2] = acc[i2][i2];
    }
}

// ---------------------------------------------------------------- triplet + finalize
template <int NZ>
__global__ __launch_bounds__(128) void triplet_kernel(
    const float* __restrict__ P, const float* __restrict__ sqpart,
    const int* __restrict__ labels, float* __restrict__ total,
    int* __restrict__ cnt, int* __restrict__ ticket, float* __restrict__ out) {
    __shared__ float Hrow[BN];
    __shared__ int   lab[BN];
    __shared__ int   poslist[BN];
    __shared__ int   npos_s;
    __shared__ float wsum[2];
    __shared__ int   wcnt[2];
    const int a   = blockIdx.x;
    const int tid = threadIdx.x;

    if (tid == 0) npos_s = 0;
    for (int i = tid; i < BN; i += 128) lab[i] = labels[i];

    if (tid < 96) {
        const int c0 = tid * 4;
        float4 g = make_float4(0.f, 0.f, 0.f, 0.f);
        float4 s = make_float4(0.f, 0.f, 0.f, 0.f);
#pragma unroll
        for (int z = 0; z < NZ; ++z) {
            const float4 pv = *(const float4*)&P[(size_t)a * ((size_t)NZ * BN) + z * BN + c0];
            const float4 sv = *(const float4*)&sqpart[z * BN + c0];
            g.x += pv.x; g.y += pv.y; g.z += pv.z; g.w += pv.w;
            s.x += sv.x; s.y += sv.y; s.z += sv.z; s.w += sv.w;
        }
        Hrow[c0 + 0] = s.x - 2.f * g.x;
        Hrow[c0 + 1] = s.y - 2.f * g.y;
        Hrow[c0 + 2] = s.z - 2.f * g.z;
        Hrow[c0 + 3] = s.w - 2.f * g.w;
    }
    __syncthreads();

    const int la = lab[a];
    int lc = 0;
#pragma unroll
    for (int q = 0; q < 3; ++q) {
        const int p = tid + q * 128;
        if (lab[p] != la) ++lc;
        else if (p > a) { const int k = atomicAdd(&npos_s, 1); poslist[k] = p; }
    }
    __syncthreads();
    const int np = npos_s;

    const float hn0 = Hrow[tid];
    const float hn1 = Hrow[tid + 128];
    const float hn2 = Hrow[tid + 256];
    const bool  ng0 = (lab[tid]       != la);
    const bool  ng1 = (lab[tid + 128] != la);
    const bool  ng2 = (lab[tid + 256] != la);

    float ls = 0.f;
    for (int k = 0; k < np; ++k) {
        const float dpm = Hrow[poslist[k]] + MARGIN;
        if (ng0) { const float v = dpm - hn0; ls += (v > 0.f) ? v : 0.f; }
        if (ng1) { const float v = dpm - hn1; ls += (v > 0.f) ? v : 0.f; }
        if (ng2) { const float v = dpm - hn2; ls += (v > 0.f) ? v : 0.f; }
    }

#pragma unroll
    for (int off = 32; off; off >>= 1) {
        ls += __shfl_down(ls, off);
        lc += __shfl_down(lc, off);
    }
    const int wave = tid >> 6, lane = tid & 63;
    if (lane == 0) { wsum[wave] = ls; wcnt[wave] = lc; }
    __syncthreads();
    if (tid == 0) {
        const float s    = wsum[0] + wsum[1];
        const int   nneg = wcnt[0] + wcnt[1];
        if (s != 0.f) atomicAdd(total, s);
        if (np)       atomicAdd(cnt, np * nneg);
        __threadfence();
        const int done = atomicAdd(ticket, 1);
        if (done == (int)gridDim.x - 1) {
            const float tot = atomicAdd(total, 0.0f);
            const int   c   = atomicAdd(cnt, 0);
            out[0] = (c > 0) ? tot / (float)c : 0.f;
            out[1] = (float)c;
        }
    }
}

extern "C" void kernel_launch(void* const* d_in, const int* in_sizes, int n_in,
                              void* d_out, int out_size, void* d_ws, size_t ws_size,
                              hipStream_t stream) {
    const float* E      = (const float*)d_in[0];
    const int*   labels = (const int*)d_in[1];
    float*       out    = (float*)d_out;

    int Z = 1;
    for (int cand : {32, 16, 8, 4, 2}) {
        size_t need = (size_t)cand * BN * BN * 4 + (size_t)cand * BN * 4 + 64;
        if (need <= ws_size) { Z = cand; break; }
    }

    char*  ws     = (char*)d_ws;
    float* P      = (float*)ws;                                     // BN x (Z*BN)
    float* sqpart = (float*)(ws + (size_t)Z * BN * BN * 4);         // Z x BN
    float* total  = (float*)(ws + (size_t)Z * BN * BN * 4 + (size_t)Z * BN * 4);
    int*   cnt    = (int*)(total + 1);
    int*   ticket = (int*)(total + 2);

    gram_kernel<<<6 * Z, 256, 0, stream>>>(E, P, sqpart, total, cnt, ticket, DIM / Z, Z);

    switch (Z) {
        case 32: triplet_kernel<32><<<BN, 128, 0, stream>>>(P, sqpart, labels, total, cnt, ticket, out); break;
        case 16: triplet_kernel<16><<<BN, 128, 0, stream>>>(P, sqpart, labels, total, cnt, ticket, out); break;
        case 8:  triplet_kernel<8> <<<BN, 128, 0, stream>>>(P, sqpart, labels, total, cnt, ticket, out); break;
        case 4:  triplet_kernel<4> <<<BN, 128, 0, stream>>>(P, sqpart, labels, total, cnt, ticket, out); break;
        case 2:  triplet_kernel<2> <<<BN, 128, 0, stream>>>(P, sqpart, labels, total, cnt, ticket, out); break;
        default: triplet_kernel<1> <<<BN, 128, 0, stream>>>(P, sqpart, labels, total, cnt, ticket, out); break;
    }
}

// Round 6
// 81.533 us; speedup vs baseline: 1.1146x; 1.1146x over previous
//
#include <hip/hip_runtime.h>

// TripletLoss: B=384, D=1024 fp32, 16 classes, margin=1.
// H[i][j] = sq[j] - 2*dot(e_i,e_j); loss = relu(H[a,p]-H[a,n]+margin) (sq[a] cancels).
// R6 = R3 structure (proven 82.3us) with Z=8:
//   gram: 36 tiles (64x64, 4x4 reg block) x Z=8 split-K = 288 blocks (1.125/CU),
//         KC=128, K-major LDS w/ XOR-16 swizzle (conflict-free), prefetch.
//   triplet: per-anchor 128-thread blocks, P[r][z][c] contiguous layout (12KB/row),
//            poslist via LDS atomics, negatives in 3 regs, ticket last-block finalize.
// NOTE R5 post-mortem: hipLaunchCooperativeKernel silently no-ops under the
// harness graph capture — do NOT use cooperative launch here.

constexpr int BN  = 384;
constexpr int DIM = 1024;
constexpr float MARGIN = 1.0f;
constexpr int LDK = 68;   // K-major LDS row stride (floats); 16B-aligned

// ---------------------------------------------------------------- gram (split-K)
// grid 36*Z, block 256 (as 16x16). Thread t stages row r=t>>2, k-quarter kq=t&3.
// LDS element (k,row) at [k*LDK + (row ^ (kq<<4))] -> conflict-free writes+reads.
__global__ __launch_bounds__(256) void gram_kernel(
    const float* __restrict__ E, float* __restrict__ P,
    float* __restrict__ sqpart, float* __restrict__ total,
    int* __restrict__ cnt, int* __restrict__ ticket, int KC, int NZ) {
    __shared__ float Ast[32 * LDK];
    __shared__ float Bst[32 * LDK];
    const int t    = threadIdx.x;
    const int tile = blockIdx.x % 36;
    const int z    = blockIdx.x / 36;
    const int ti   = tile / 6, tj = tile % 6;
    const int i0   = ti * 64, j0 = tj * 64;

    if (blockIdx.x == 0 && t == 0) { *total = 0.f; *cnt = 0; *ticket = 0; }

    const int r  = t >> 2;              // 0..63 staged row
    const int kq = t & 3;               // 0..3  k-quarter (8 k's)
    const int kb = kq * 8;
    const int rs = r ^ (kq << 4);       // swizzled LDS row

    const float* Ab = E + (size_t)(i0 + r) * DIM + z * KC + kb;
    const float* Bb = E + (size_t)(j0 + r) * DIM + z * KC + kb;

    float4 a0 = *(const float4*)(Ab);
    float4 a1 = *(const float4*)(Ab + 4);
    float4 b0 = *(const float4*)(Bb);
    float4 b1 = *(const float4*)(Bb + 4);

    const int tx = t & 15, ty = t >> 4;
    float acc[4][4] = {};

    for (int kt = 0; kt < KC; kt += 32) {
        Ast[(kb + 0) * LDK + rs] = a0.x; Ast[(kb + 1) * LDK + rs] = a0.y;
        Ast[(kb + 2) * LDK + rs] = a0.z; Ast[(kb + 3) * LDK + rs] = a0.w;
        Ast[(kb + 4) * LDK + rs] = a1.x; Ast[(kb + 5) * LDK + rs] = a1.y;
        Ast[(kb + 6) * LDK + rs] = a1.z; Ast[(kb + 7) * LDK + rs] = a1.w;
        Bst[(kb + 0) * LDK + rs] = b0.x; Bst[(kb + 1) * LDK + rs] = b0.y;
        Bst[(kb + 2) * LDK + rs] = b0.z; Bst[(kb + 3) * LDK + rs] = b0.w;
        Bst[(kb + 4) * LDK + rs] = b1.x; Bst[(kb + 5) * LDK + rs] = b1.y;
        Bst[(kb + 6) * LDK + rs] = b1.z; Bst[(kb + 7) * LDK + rs] = b1.w;
        __syncthreads();
        if (kt + 32 < KC) {             // prefetch next chunk
            a0 = *(const float4*)(Ab + kt + 32);
            a1 = *(const float4*)(Ab + kt + 36);
            b0 = *(const float4*)(Bb + kt + 32);
            b1 = *(const float4*)(Bb + kt + 36);
        }
#pragma unroll
        for (int kk = 0; kk < 32; ++kk) {
            const int sw = (kk >> 3) << 4;
            const float4 av = *(const float4*)&Ast[kk * LDK + ((4 * ty) ^ sw)];
            const float4 bv = *(const float4*)&Bst[kk * LDK + ((4 * tx) ^ sw)];
            const float aa[4] = {av.x, av.y, av.z, av.w};
            const float bb[4] = {bv.x, bv.y, bv.z, bv.w};
#pragma unroll
            for (int i2 = 0; i2 < 4; ++i2)
#pragma unroll
                for (int j2 = 0; j2 < 4; ++j2)
                    acc[i2][j2] += aa[i2] * bb[j2];
        }
        __syncthreads();
    }

    const size_t rowstride = (size_t)NZ * BN;
#pragma unroll
    for (int i2 = 0; i2 < 4; ++i2) {
        *(float4*)&P[(size_t)(i0 + 4 * ty + i2) * rowstride + (size_t)z * BN + (j0 + 4 * tx)] =
            make_float4(acc[i2][0], acc[i2][1], acc[i2][2], acc[i2][3]);
    }
    if (ti == tj && tx == ty) {         // diagonal -> sq partials
#pragma unroll
        for (int i2 = 0; i2 < 4; ++i2)
            sqpart[z * BN + (i0 + 4 * ty + i2)] = acc[i2][i2];
    }
}

// ---------------------------------------------------------------- triplet + finalize
template <int NZ>
__global__ __launch_bounds__(128) void triplet_kernel(
    const float* __restrict__ P, const float* __restrict__ sqpart,
    const int* __restrict__ labels, float* __restrict__ total,
    int* __restrict__ cnt, int* __restrict__ ticket, float* __restrict__ out) {
    __shared__ float Hrow[BN];
    __shared__ int   lab[BN];
    __shared__ int   poslist[BN];
    __shared__ int   npos_s;
    __shared__ float wsum[2];
    __shared__ int   wcnt[2];
    const int a   = blockIdx.x;
    const int tid = threadIdx.x;

    if (tid == 0) npos_s = 0;
    for (int i = tid; i < BN; i += 128) lab[i] = labels[i];

    if (tid < 96) {
        const int c0 = tid * 4;
        float4 g = make_float4(0.f, 0.f, 0.f, 0.f);
        float4 s = make_float4(0.f, 0.f, 0.f, 0.f);
#pragma unroll
        for (int z = 0; z < NZ; ++z) {
            const float4 pv = *(const float4*)&P[(size_t)a * ((size_t)NZ * BN) + z * BN + c0];
            const float4 sv = *(const float4*)&sqpart[z * BN + c0];
            g.x += pv.x; g.y += pv.y; g.z += pv.z; g.w += pv.w;
            s.x += sv.x; s.y += sv.y; s.z += sv.z; s.w += sv.w;
        }
        Hrow[c0 + 0] = s.x - 2.f * g.x;
        Hrow[c0 + 1] = s.y - 2.f * g.y;
        Hrow[c0 + 2] = s.z - 2.f * g.z;
        Hrow[c0 + 3] = s.w - 2.f * g.w;
    }
    __syncthreads();

    const int la = lab[a];
    int lc = 0;
#pragma unroll
    for (int q = 0; q < 3; ++q) {
        const int p = tid + q * 128;
        if (lab[p] != la) ++lc;
        else if (p > a) { const int k = atomicAdd(&npos_s, 1); poslist[k] = p; }
    }
    __syncthreads();
    const int np = npos_s;

    const float hn0 = Hrow[tid];
    const float hn1 = Hrow[tid + 128];
    const float hn2 = Hrow[tid + 256];
    const bool  ng0 = (lab[tid]       != la);
    const bool  ng1 = (lab[tid + 128] != la);
    const bool  ng2 = (lab[tid + 256] != la);

    float ls = 0.f;
    for (int k = 0; k < np; ++k) {
        const float dpm = Hrow[poslist[k]] + MARGIN;
        if (ng0) { const float v = dpm - hn0; ls += (v > 0.f) ? v : 0.f; }
        if (ng1) { const float v = dpm - hn1; ls += (v > 0.f) ? v : 0.f; }
        if (ng2) { const float v = dpm - hn2; ls += (v > 0.f) ? v : 0.f; }
    }

#pragma unroll
    for (int off = 32; off; off >>= 1) {
        ls += __shfl_down(ls, off);
        lc += __shfl_down(lc, off);
    }
    const int wave = tid >> 6, lane = tid & 63;
    if (lane == 0) { wsum[wave] = ls; wcnt[wave] = lc; }
    __syncthreads();
    if (tid == 0) {
        const float s    = wsum[0] + wsum[1];
        const int   nneg = wcnt[0] + wcnt[1];
        if (s != 0.f) atomicAdd(total, s);
        if (np)       atomicAdd(cnt, np * nneg);
        __threadfence();
        const int done = atomicAdd(ticket, 1);
        if (done == (int)gridDim.x - 1) {       // last block: finalize
            const float tot = atomicAdd(total, 0.0f);
            const int   c   = atomicAdd(cnt, 0);
            out[0] = (c > 0) ? tot / (float)c : 0.f;
            out[1] = (float)c;
        }
    }
}

extern "C" void kernel_launch(void* const* d_in, const int* in_sizes, int n_in,
                              void* d_out, int out_size, void* d_ws, size_t ws_size,
                              hipStream_t stream) {
    const float* E      = (const float*)d_in[0];
    const int*   labels = (const int*)d_in[1];
    float*       out    = (float*)d_out;

    int Z = 1;
    for (int cand : {8, 4, 2}) {
        size_t need = (size_t)cand * BN * BN * 4 + (size_t)cand * BN * 4 + 64;
        if (need <= ws_size) { Z = cand; break; }
    }

    char*  ws     = (char*)d_ws;
    float* P      = (float*)ws;                                     // BN x (Z*BN)
    float* sqpart = (float*)(ws + (size_t)Z * BN * BN * 4);         // Z x BN
    float* total  = (float*)(ws + (size_t)Z * BN * BN * 4 + (size_t)Z * BN * 4);
    int*   cnt    = (int*)(total + 1);
    int*   ticket = (int*)(total + 2);

    gram_kernel<<<36 * Z, 256, 0, stream>>>(E, P, sqpart, total, cnt, ticket, DIM / Z, Z);

    switch (Z) {
        case 8:  triplet_kernel<8><<<BN, 128, 0, stream>>>(P, sqpart, labels, total, cnt, ticket, out); break;
        case 4:  triplet_kernel<4><<<BN, 128, 0, stream>>>(P, sqpart, labels, total, cnt, ticket, out); break;
        case 2:  triplet_kernel<2><<<BN, 128, 0, stream>>>(P, sqpart, labels, total, cnt, ticket, out); break;
        default: triplet_kernel<1><<<BN, 128, 0, stream>>>(P, sqpart, labels, total, cnt, ticket, out); break;
    }
}